// Round 1
// baseline (838.530 us; speedup 1.0000x reference)
//
#include <hip/hip_runtime.h>
#include <hip/hip_fp16.h>

// ---------------------------------------------------------------------------
// Int4Linear: out[b,s,n] = sum_k x[b,s,k] * deq(w)[n,k] + bias[n]
//   x: f32 (fp16-valued) [4096, 4096]   (M=B*S=4096, K=4096)
//   weight_packed: int32 (byte values) [11008, 2048]  (2 int4 codes per byte)
//   scales: f32 [11008, 32]  (group_size=128)
//   bias: f32 [11008]
//   out: f32 [4096, 11008]
// Plan: pre-pass converts x -> fp16 and dequantizes w -> fp16 (both in d_ws),
// then m97-style 128x128 MFMA GEMM (fp16 16x16x32, global_load_lds w=16).
// ---------------------------------------------------------------------------

typedef _Float16 half8 __attribute__((ext_vector_type(8)));
typedef float floatx4 __attribute__((ext_vector_type(4)));

#define M_DIM 4096
#define N_DIM 11008
#define K_DIM 4096

// ---- Kernel 1: x f32 -> fp16 (exact: values are fp16-representable) -------
__global__ __launch_bounds__(256) void cvt_x_kernel(const float* __restrict__ x,
                                                    _Float16* __restrict__ xh) {
    int i = (blockIdx.x * 256 + threadIdx.x) * 8;
    float4 v0 = *(const float4*)(x + i);
    float4 v1 = *(const float4*)(x + i + 4);
    half8 h;
    h[0] = (_Float16)v0.x; h[1] = (_Float16)v0.y;
    h[2] = (_Float16)v0.z; h[3] = (_Float16)v0.w;
    h[4] = (_Float16)v1.x; h[5] = (_Float16)v1.y;
    h[6] = (_Float16)v1.z; h[7] = (_Float16)v1.w;
    *(half8*)(xh + i) = h;
}

// ---- Kernel 2: dequant w -> fp16 [11008][4096] -----------------------------
// pair index pi in [0, 11008*2048); each thread does 4 pairs -> 8 fp16 out.
__global__ __launch_bounds__(256) void dequant_w_kernel(const int* __restrict__ wp,
                                                        const float* __restrict__ scales,
                                                        _Float16* __restrict__ wh) {
    int t = blockIdx.x * 256 + threadIdx.x;
    int pi = t * 4;                    // pair index
    int n = pi >> 11;                  // / 2048 pairs per row
    int i = pi & 2047;                 // pair within row
    float s = scales[(n << 5) + (i >> 6)];   // group = (2i)/128 = i/64
    int4 p = *(const int4*)(wp + pi);
    half8 h;
    h[0] = (_Float16)((float)((p.x & 0xF) - 8) * s);
    h[1] = (_Float16)((float)(((p.x >> 4) & 0xF) - 8) * s);
    h[2] = (_Float16)((float)((p.y & 0xF) - 8) * s);
    h[3] = (_Float16)((float)(((p.y >> 4) & 0xF) - 8) * s);
    h[4] = (_Float16)((float)((p.z & 0xF) - 8) * s);
    h[5] = (_Float16)((float)(((p.z >> 4) & 0xF) - 8) * s);
    h[6] = (_Float16)((float)((p.w & 0xF) - 8) * s);
    h[7] = (_Float16)((float)(((p.w >> 4) & 0xF) - 8) * s);
    *(half8*)(wh + (size_t)pi * 2) = h;
}

// ---- Kernel 3: GEMM C = A * B^T + bias ------------------------------------
// A: [M][K] fp16, B: [N][K] fp16 (row-major over K), C: [M][N] f32.
// 128x128 tile, BK=32, 4 waves (2x2), each wave 64x64 = 4x4 frags of 16x16.
__global__ __launch_bounds__(256) void gemm_kernel(const _Float16* __restrict__ A,
                                                   const _Float16* __restrict__ B,
                                                   const float* __restrict__ bias,
                                                   float* __restrict__ C) {
    __shared__ __align__(16) _Float16 sA[128 * 32];
    __shared__ __align__(16) _Float16 sB[128 * 32];

    const int tid  = threadIdx.x;
    const int lane = tid & 63;
    const int w    = tid >> 6;          // wave 0..3
    const int m0   = blockIdx.y * 128;  // output row base
    const int n0   = blockIdx.x * 128;  // output col base

    // staging geometry: each global_load_lds stages 1024B = 16 rows of 64B.
    // chunk = w*2 + c covers rows [chunk*16, chunk*16+16).
    // lane covers row_in_chunk = lane>>2, k-slot = lane&3 (8 fp16 = 16B).
    const int rA = lane >> 2;
    const int kq = (lane & 3) * 8;

    // fragment geometry
    const int wr = (w >> 1) * 64;       // wave row base in tile
    const int wc = (w & 1) * 64;        // wave col base in tile
    const int fr = lane & 15;           // frag row/col
    const int fq = (lane >> 4) * 8;     // frag k offset

    floatx4 acc[4][4];
    for (int mi = 0; mi < 4; ++mi)
        for (int ni = 0; ni < 4; ++ni)
            acc[mi][ni] = (floatx4){0.f, 0.f, 0.f, 0.f};

    for (int kt = 0; kt < K_DIM; kt += 32) {
        // stage A and B tiles (128x32 fp16 each) via async global->LDS
        for (int c = 0; c < 2; ++c) {
            const int chunk = w * 2 + c;
            const int row = chunk * 16 + rA;
            const _Float16* srcA = A + (size_t)(m0 + row) * K_DIM + kt + kq;
            const _Float16* srcB = B + (size_t)(n0 + row) * K_DIM + kt + kq;
            __builtin_amdgcn_global_load_lds(
                (const __attribute__((address_space(1))) void*)srcA,
                (__attribute__((address_space(3))) void*)&sA[chunk * 512], 16, 0, 0);
            __builtin_amdgcn_global_load_lds(
                (const __attribute__((address_space(1))) void*)srcB,
                (__attribute__((address_space(3))) void*)&sB[chunk * 512], 16, 0, 0);
        }
        __syncthreads();   // drains vmcnt then barrier: LDS tiles ready

        half8 af[4], bf[4];
        for (int mi = 0; mi < 4; ++mi)
            af[mi] = *(const half8*)&sA[(wr + mi * 16 + fr) * 32 + fq];
        for (int ni = 0; ni < 4; ++ni)
            bf[ni] = *(const half8*)&sB[(wc + ni * 16 + fr) * 32 + fq];

        for (int mi = 0; mi < 4; ++mi)
            for (int ni = 0; ni < 4; ++ni)
                acc[mi][ni] = __builtin_amdgcn_mfma_f32_16x16x32_f16(
                    af[mi], bf[ni], acc[mi][ni], 0, 0, 0);

        __syncthreads();   // protect LDS before next stage overwrites
    }

    // epilogue: C/D layout col = lane&15, row = (lane>>4)*4 + reg
    for (int mi = 0; mi < 4; ++mi) {
        const int row = m0 + wr + mi * 16 + (lane >> 4) * 4;
        for (int ni = 0; ni < 4; ++ni) {
            const int col = n0 + wc + ni * 16 + fr;
            const float b = bias[col];
            float* cp = C + (size_t)row * N_DIM + col;
            for (int r = 0; r < 4; ++r)
                cp[(size_t)r * N_DIM] = acc[mi][ni][r] + b;
        }
    }
}

extern "C" void kernel_launch(void* const* d_in, const int* in_sizes, int n_in,
                              void* d_out, int out_size, void* d_ws, size_t ws_size,
                              hipStream_t stream) {
    const float* x      = (const float*)d_in[0];
    const int*   wp     = (const int*)d_in[1];
    const float* scales = (const float*)d_in[2];
    const float* bias   = (const float*)d_in[3];
    float* out = (float*)d_out;

    _Float16* xh = (_Float16*)d_ws;                          // 33,554,432 B
    _Float16* wh = (_Float16*)((char*)d_ws + 33554432ull);   // 90,177,536 B

    // x: 16,777,216 elems / 8 per thread / 256 per block = 8192 blocks
    cvt_x_kernel<<<8192, 256, 0, stream>>>(x, xh);
    // w: 22,544,384 pairs / 4 per thread / 256 per block = 22016 blocks
    dequant_w_kernel<<<22016, 256, 0, stream>>>(wp, scales, wh);

    dim3 grid(N_DIM / 128, M_DIM / 128);   // 86 x 32
    gemm_kernel<<<grid, 256, 0, stream>>>(xh, wh, bias, out);
}

// Round 2
// 761.743 us; speedup vs baseline: 1.1008x; 1.1008x over previous
//
#include <hip/hip_runtime.h>
#include <hip/hip_fp16.h>

// ---------------------------------------------------------------------------
// Int4Linear on MI355X:
//   pre-pass 1: x f32 -> fp16 (exact)
//   pre-pass 2: dequant int4 w -> fp16 [N][K]
//   GEMM: 256x256 tile, BK=32, 3-buffer LDS pipeline with counted vmcnt
//         (never drains to 0 in main loop), raw s_barrier (1 per K-tile),
//         T2 source-side XOR swizzle, T5 setprio, T1 XCD swizzle.
// ---------------------------------------------------------------------------

typedef _Float16 half8 __attribute__((ext_vector_type(8)));
typedef float floatx4 __attribute__((ext_vector_type(4)));

#define M_DIM 4096
#define N_DIM 11008
#define K_DIM 4096
#define KTILES 128   // K / 32

// ---- Kernel 1: x f32 -> fp16 ----------------------------------------------
__global__ __launch_bounds__(256) void cvt_x_kernel(const float* __restrict__ x,
                                                    _Float16* __restrict__ xh) {
    int i = (blockIdx.x * 256 + threadIdx.x) * 8;
    float4 v0 = *(const float4*)(x + i);
    float4 v1 = *(const float4*)(x + i + 4);
    half8 h;
    h[0] = (_Float16)v0.x; h[1] = (_Float16)v0.y;
    h[2] = (_Float16)v0.z; h[3] = (_Float16)v0.w;
    h[4] = (_Float16)v1.x; h[5] = (_Float16)v1.y;
    h[6] = (_Float16)v1.z; h[7] = (_Float16)v1.w;
    *(half8*)(xh + i) = h;
}

// ---- Kernel 2: dequant w -> fp16 [11008][4096] -----------------------------
__global__ __launch_bounds__(256) void dequant_w_kernel(const int* __restrict__ wp,
                                                        const float* __restrict__ scales,
                                                        _Float16* __restrict__ wh) {
    int t = blockIdx.x * 256 + threadIdx.x;
    int pi = t * 4;                    // pair index
    int n = pi >> 11;                  // / 2048 pairs per row
    int i = pi & 2047;                 // pair within row
    float s = scales[(n << 5) + (i >> 6)];   // group = i/64
    int4 p = *(const int4*)(wp + pi);
    half8 h;
    h[0] = (_Float16)((float)((p.x & 0xF) - 8) * s);
    h[1] = (_Float16)((float)(((p.x >> 4) & 0xF) - 8) * s);
    h[2] = (_Float16)((float)((p.y & 0xF) - 8) * s);
    h[3] = (_Float16)((float)(((p.y >> 4) & 0xF) - 8) * s);
    h[4] = (_Float16)((float)((p.z & 0xF) - 8) * s);
    h[5] = (_Float16)((float)(((p.z >> 4) & 0xF) - 8) * s);
    h[6] = (_Float16)((float)((p.w & 0xF) - 8) * s);
    h[7] = (_Float16)((float)(((p.w >> 4) & 0xF) - 8) * s);
    *(half8*)(wh + (size_t)pi * 2) = h;
}

// ---- Kernel 3: GEMM C = A * B^T + bias ------------------------------------
// LDS layout per buffer: [256 rows][4 slots of 8 fp16]; LDS[row][slot] holds
// global slot (slot ^ ((row>>1)&3))  -> bank-conflict-free ds_read_b128.
// global_load_lds writes linearly (base + lane*16B), so the swizzle is
// carried on the per-lane GLOBAL source address (rule #21).

#define GLDS(SRC, DST) __builtin_amdgcn_global_load_lds( \
    (const __attribute__((address_space(1))) void*)(SRC), \
    (__attribute__((address_space(3))) void*)(DST), 16, 0, 0)

__global__ __launch_bounds__(512) void gemm_kernel(const _Float16* __restrict__ A,
                                                   const _Float16* __restrict__ B,
                                                   const float* __restrict__ bias,
                                                   float* __restrict__ C) {
    __shared__ __align__(16) _Float16 sA[3 * 8192];   // 3 bufs x 256x32
    __shared__ __align__(16) _Float16 sB[3 * 8192];

    const int tid = threadIdx.x;
    const int l = tid & 63;
    const int w = tid >> 6;            // wave 0..7

    // T1: bijective XCD swizzle. 688 blocks = 8 XCDs x 86; each XCD owns
    // 2 M-rows (mt = xcd*2 + bit), walking all 43 N-tiles.
    const int bid = blockIdx.x;
    const int mt = (bid & 7) * 2 + ((bid >> 3) & 1);   // 0..15
    const int ntile = bid >> 4;                        // 0..42
    const int m0 = mt * 256;
    const int n0 = ntile * 256;

    // wave tile: 128(M) x 64(N); 8x4 frags of 16x16
    const int wr = (w >> 2) * 128;
    const int wc = (w & 3) * 64;
    const int fr = l & 15;
    // swizzled read slot (elem offset): (lane>>4) ^ ((row>>1)&3), row = ..+fr
    const int slot_sw = ((l >> 4) ^ ((fr >> 1) & 3)) * 8;

    // staging: round r covers rows r*128..r*128+127; lane row = w*16 + (l>>2),
    // dest slot = l&3, source k-slot = (l&3) ^ ((row>>1)&3) = (l&3)^((l>>3)&3)
    const int srow = w * 16 + (l >> 2);
    const int skq = ((l & 3) ^ ((l >> 3) & 3)) * 8;
    const _Float16* a0 = A + (size_t)(m0 + srow) * K_DIM + skq;
    const _Float16* b0 = B + (size_t)(n0 + srow) * K_DIM + skq;
    const int sdst = w * 512;          // wave-uniform LDS dest (elems)

    floatx4 acc[8][4];
    #pragma unroll
    for (int mi = 0; mi < 8; ++mi)
        #pragma unroll
        for (int ni = 0; ni < 4; ++ni)
            acc[mi][ni] = (floatx4){0.f, 0.f, 0.f, 0.f};

    // prologue: stage tile 0 -> buf0, tile 1 -> buf1 (4 loads/thread each)
    GLDS(a0,                       &sA[sdst]);
    GLDS(b0,                       &sB[sdst]);
    GLDS(a0 + (size_t)128 * K_DIM, &sA[4096 + sdst]);
    GLDS(b0 + (size_t)128 * K_DIM, &sB[4096 + sdst]);
    GLDS(a0 + 32,                       &sA[8192 + sdst]);
    GLDS(b0 + 32,                       &sB[8192 + sdst]);
    GLDS(a0 + 32 + (size_t)128 * K_DIM, &sA[8192 + 4096 + sdst]);
    GLDS(b0 + 32 + (size_t)128 * K_DIM, &sB[8192 + 4096 + sdst]);

    int bufc = 0, bufs = 2;
    int ks = 64;
    for (int t = 0; t < KTILES; ++t) {
        // T4: counted wait. Outstanding at entry: tile t+1's 4 loads.
        if (t < KTILES - 1) asm volatile("s_waitcnt vmcnt(4)" ::: "memory");
        else                asm volatile("s_waitcnt vmcnt(0)" ::: "memory");
        __builtin_amdgcn_s_barrier();
        asm volatile("" ::: "memory");

        // prefetch tile t+2 into buf (t+2)%3 == (t-1)%3 (consumed last iter;
        // all waves drained their reads of it before passing this barrier)
        if (t + 2 < KTILES) {
            GLDS(a0 + ks,                       &sA[bufs * 8192 + sdst]);
            GLDS(b0 + ks,                       &sB[bufs * 8192 + sdst]);
            GLDS(a0 + ks + (size_t)128 * K_DIM, &sA[bufs * 8192 + 4096 + sdst]);
            GLDS(b0 + ks + (size_t)128 * K_DIM, &sB[bufs * 8192 + 4096 + sdst]);
            ks += 32;
        }

        const _Float16* pA = sA + bufc * 8192;
        const _Float16* pB = sB + bufc * 8192;
        half8 af[8], bf[4];
        #pragma unroll
        for (int mi = 0; mi < 8; ++mi)
            af[mi] = *(const half8*)&pA[(wr + mi * 16 + fr) * 32 + slot_sw];
        #pragma unroll
        for (int ni = 0; ni < 4; ++ni)
            bf[ni] = *(const half8*)&pB[(wc + ni * 16 + fr) * 32 + slot_sw];

        __builtin_amdgcn_s_setprio(1);   // T5
        #pragma unroll
        for (int mi = 0; mi < 8; ++mi)
            #pragma unroll
            for (int ni = 0; ni < 4; ++ni)
                acc[mi][ni] = __builtin_amdgcn_mfma_f32_16x16x32_f16(
                    af[mi], bf[ni], acc[mi][ni], 0, 0, 0);
        __builtin_amdgcn_s_setprio(0);

        bufc = (bufc == 2) ? 0 : bufc + 1;
        bufs = (bufs == 2) ? 0 : bufs + 1;
    }

    // epilogue: C/D layout col = lane&15, row = (lane>>4)*4 + reg
    #pragma unroll
    for (int ni = 0; ni < 4; ++ni) {
        const int col = n0 + wc + ni * 16 + fr;
        const float bv = bias[col];
        #pragma unroll
        for (int mi = 0; mi < 8; ++mi) {
            float* cp = C + (size_t)(m0 + wr + mi * 16 + (l >> 4) * 4) * N_DIM + col;
            cp[0]                  = acc[mi][ni][0] + bv;
            cp[(size_t)N_DIM]      = acc[mi][ni][1] + bv;
            cp[(size_t)2 * N_DIM]  = acc[mi][ni][2] + bv;
            cp[(size_t)3 * N_DIM]  = acc[mi][ni][3] + bv;
        }
    }
}

extern "C" void kernel_launch(void* const* d_in, const int* in_sizes, int n_in,
                              void* d_out, int out_size, void* d_ws, size_t ws_size,
                              hipStream_t stream) {
    const float* x      = (const float*)d_in[0];
    const int*   wp     = (const int*)d_in[1];
    const float* scales = (const float*)d_in[2];
    const float* bias   = (const float*)d_in[3];
    float* out = (float*)d_out;

    _Float16* xh = (_Float16*)d_ws;                          // 33,554,432 B
    _Float16* wh = (_Float16*)((char*)d_ws + 33554432ull);   // 90,177,536 B

    cvt_x_kernel<<<8192, 256, 0, stream>>>(x, xh);
    dequant_w_kernel<<<22016, 256, 0, stream>>>(wp, scales, wh);

    // 16 Mtiles x 43 Ntiles = 688 blocks (= 8 XCDs x 86 exactly)
    gemm_kernel<<<688, 512, 0, stream>>>(xh, wh, bias, out);
}

// Round 6
// 745.877 us; speedup vs baseline: 1.1242x; 1.0213x over previous
//
#include <hip/hip_runtime.h>
#include <hip/hip_fp16.h>

// ---------------------------------------------------------------------------
// Int4Linear on MI355X:
//   pre-pass 1: x f32 -> fp16 (exact)      [grid-stride]
//   pre-pass 2: dequant int4 w -> fp16     [grid-stride]
//   GEMM: 256x256 tile, BK=32, 3-buffer LDS pipeline, counted vmcnt (never 0
//         in main loop), 1 raw barrier/K-tile, source-side XOR swizzle
//         (0 bank conflicts, verified r2), XCD swizzle, and NEW in r3:
//         software-pipelined mi-loop (ds_read af[mi+1] overlaps MFMA af[mi]).
//   (r5 resubmission — r3/r4/r5 benches were GPUAcquisitionTimeout, never ran.)
// ---------------------------------------------------------------------------

typedef _Float16 half8 __attribute__((ext_vector_type(8)));
typedef float floatx4 __attribute__((ext_vector_type(4)));

#define M_DIM 4096
#define N_DIM 11008
#define K_DIM 4096
#define KTILES 128   // K / 32

// ---- Kernel 1: x f32 -> fp16 ----------------------------------------------
__global__ __launch_bounds__(256) void cvt_x_kernel(const float* __restrict__ x,
                                                    _Float16* __restrict__ xh) {
    const int stride = gridDim.x * 256;
    for (int t = blockIdx.x * 256 + threadIdx.x; t < (M_DIM * K_DIM) / 8; t += stride) {
        int i = t * 8;
        float4 v0 = *(const float4*)(x + i);
        float4 v1 = *(const float4*)(x + i + 4);
        half8 h;
        h[0] = (_Float16)v0.x; h[1] = (_Float16)v0.y;
        h[2] = (_Float16)v0.z; h[3] = (_Float16)v0.w;
        h[4] = (_Float16)v1.x; h[5] = (_Float16)v1.y;
        h[6] = (_Float16)v1.z; h[7] = (_Float16)v1.w;
        *(half8*)(xh + i) = h;
    }
}

// ---- Kernel 2: dequant w -> fp16 [11008][4096] -----------------------------
__global__ __launch_bounds__(256) void dequant_w_kernel(const int* __restrict__ wp,
                                                        const float* __restrict__ scales,
                                                        _Float16* __restrict__ wh) {
    const int stride = gridDim.x * 256;
    const int npairs4 = (N_DIM * (K_DIM / 2)) / 4;   // threads of 4 pairs
    for (int t = blockIdx.x * 256 + threadIdx.x; t < npairs4; t += stride) {
        int pi = t * 4;                    // pair index
        int n = pi >> 11;                  // / 2048 pairs per row
        int i = pi & 2047;                 // pair within row
        float s = scales[(n << 5) + (i >> 6)];   // group = i/64
        int4 p = *(const int4*)(wp + pi);
        half8 h;
        h[0] = (_Float16)((float)((p.x & 0xF) - 8) * s);
        h[1] = (_Float16)((float)(((p.x >> 4) & 0xF) - 8) * s);
        h[2] = (_Float16)((float)((p.y & 0xF) - 8) * s);
        h[3] = (_Float16)((float)(((p.y >> 4) & 0xF) - 8) * s);
        h[4] = (_Float16)((float)((p.z & 0xF) - 8) * s);
        h[5] = (_Float16)((float)(((p.z >> 4) & 0xF) - 8) * s);
        h[6] = (_Float16)((float)((p.w & 0xF) - 8) * s);
        h[7] = (_Float16)((float)(((p.w >> 4) & 0xF) - 8) * s);
        *(half8*)(wh + (size_t)pi * 2) = h;
    }
}

// ---- Kernel 3: GEMM C = A * B^T + bias ------------------------------------
#define GLDS(SRC, DST) __builtin_amdgcn_global_load_lds( \
    (const __attribute__((address_space(1))) void*)(SRC), \
    (__attribute__((address_space(3))) void*)(DST), 16, 0, 0)

__global__ __launch_bounds__(512) void gemm_kernel(const _Float16* __restrict__ A,
                                                   const _Float16* __restrict__ B,
                                                   const float* __restrict__ bias,
                                                   float* __restrict__ C) {
    __shared__ __align__(16) _Float16 sA[3 * 8192];   // 3 bufs x 256x32
    __shared__ __align__(16) _Float16 sB[3 * 8192];

    const int tid = threadIdx.x;
    const int l = tid & 63;
    const int w = tid >> 6;            // wave 0..7

    // T1: bijective XCD swizzle. 688 blocks = 8 XCDs x 86.
    const int bid = blockIdx.x;
    const int mt = (bid & 7) * 2 + ((bid >> 3) & 1);   // 0..15
    const int ntile = bid >> 4;                        // 0..42
    const int m0 = mt * 256;
    const int n0 = ntile * 256;

    // wave tile: 128(M) x 64(N); 8x4 frags of 16x16
    const int wr = (w >> 2) * 128;
    const int wc = (w & 3) * 64;
    const int fr = l & 15;
    const int slot_sw = ((l >> 4) ^ ((fr >> 1) & 3)) * 8;  // swizzled read slot

    // staging: lane row = w*16 + (l>>2), source k-slot pre-swizzled
    const int srow = w * 16 + (l >> 2);
    const int skq = ((l & 3) ^ ((l >> 3) & 3)) * 8;
    const _Float16* a0 = A + (size_t)(m0 + srow) * K_DIM + skq;
    const _Float16* b0 = B + (size_t)(n0 + srow) * K_DIM + skq;
    const int sdst = w * 512;          // wave-uniform LDS dest (elems)

    floatx4 acc[8][4];
    #pragma unroll
    for (int mi = 0; mi < 8; ++mi)
        #pragma unroll
        for (int ni = 0; ni < 4; ++ni)
            acc[mi][ni] = (floatx4){0.f, 0.f, 0.f, 0.f};

    // prologue: stage tile 0 -> buf0, tile 1 -> buf1
    GLDS(a0,                       &sA[sdst]);
    GLDS(b0,                       &sB[sdst]);
    GLDS(a0 + (size_t)128 * K_DIM, &sA[4096 + sdst]);
    GLDS(b0 + (size_t)128 * K_DIM, &sB[4096 + sdst]);
    GLDS(a0 + 32,                       &sA[8192 + sdst]);
    GLDS(b0 + 32,                       &sB[8192 + sdst]);
    GLDS(a0 + 32 + (size_t)128 * K_DIM, &sA[8192 + 4096 + sdst]);
    GLDS(b0 + 32 + (size_t)128 * K_DIM, &sB[8192 + 4096 + sdst]);

    int bufc = 0, bufs = 2;
    int ks = 64;
    for (int t = 0; t < KTILES; ++t) {
        // T4: counted wait. Outstanding at entry: tile t+1's 4 loads.
        if (t < KTILES - 1) asm volatile("s_waitcnt vmcnt(4)" ::: "memory");
        else                asm volatile("s_waitcnt vmcnt(0)" ::: "memory");
        __builtin_amdgcn_s_barrier();
        asm volatile("" ::: "memory");

        // prefetch tile t+2 into buf (t-1)%3 (reads of it drained pre-barrier)
        if (t + 2 < KTILES) {
            GLDS(a0 + ks,                       &sA[bufs * 8192 + sdst]);
            GLDS(b0 + ks,                       &sB[bufs * 8192 + sdst]);
            GLDS(a0 + ks + (size_t)128 * K_DIM, &sA[bufs * 8192 + 4096 + sdst]);
            GLDS(b0 + ks + (size_t)128 * K_DIM, &sB[bufs * 8192 + 4096 + sdst]);
            ks += 32;
        }

        const _Float16* pA = sA + bufc * 8192;
        const _Float16* pB = sB + bufc * 8192;

        // r3: software-pipelined mi-loop. bf[0..3]+af[0] up front; then
        // each step overlaps ds_read of af[mi+1] with the 4 MFMAs of af[mi].
        half8 bf[4];
        #pragma unroll
        for (int ni = 0; ni < 4; ++ni)
            bf[ni] = *(const half8*)&pB[(wc + ni * 16 + fr) * 32 + slot_sw];
        half8 a_cur = *(const half8*)&pA[(wr + fr) * 32 + slot_sw];

        #pragma unroll
        for (int mi = 0; mi < 8; ++mi) {
            half8 a_nxt;
            if (mi < 7)
                a_nxt = *(const half8*)&pA[(wr + (mi + 1) * 16 + fr) * 32 + slot_sw];
            __builtin_amdgcn_s_setprio(1);   // T5: MFMA cluster only
            acc[mi][0] = __builtin_amdgcn_mfma_f32_16x16x32_f16(a_cur, bf[0], acc[mi][0], 0, 0, 0);
            acc[mi][1] = __builtin_amdgcn_mfma_f32_16x16x32_f16(a_cur, bf[1], acc[mi][1], 0, 0, 0);
            acc[mi][2] = __builtin_amdgcn_mfma_f32_16x16x32_f16(a_cur, bf[2], acc[mi][2], 0, 0, 0);
            acc[mi][3] = __builtin_amdgcn_mfma_f32_16x16x32_f16(a_cur, bf[3], acc[mi][3], 0, 0, 0);
            __builtin_amdgcn_s_setprio(0);
            if (mi < 7) a_cur = a_nxt;
        }

        bufc = (bufc == 2) ? 0 : bufc + 1;
        bufs = (bufs == 2) ? 0 : bufs + 1;
    }

    // epilogue: C/D layout col = lane&15, row = (lane>>4)*4 + reg
    #pragma unroll
    for (int ni = 0; ni < 4; ++ni) {
        const int col = n0 + wc + ni * 16 + fr;
        const float bv = bias[col];
        #pragma unroll
        for (int mi = 0; mi < 8; ++mi) {
            float* cp = C + (size_t)(m0 + wr + mi * 16 + (l >> 4) * 4) * N_DIM + col;
            cp[0]                  = acc[mi][ni][0] + bv;
            cp[(size_t)N_DIM]      = acc[mi][ni][1] + bv;
            cp[(size_t)2 * N_DIM]  = acc[mi][ni][2] + bv;
            cp[(size_t)3 * N_DIM]  = acc[mi][ni][3] + bv;
        }
    }
}

extern "C" void kernel_launch(void* const* d_in, const int* in_sizes, int n_in,
                              void* d_out, int out_size, void* d_ws, size_t ws_size,
                              hipStream_t stream) {
    const float* x      = (const float*)d_in[0];
    const int*   wp     = (const int*)d_in[1];
    const float* scales = (const float*)d_in[2];
    const float* bias   = (const float*)d_in[3];
    float* out = (float*)d_out;

    _Float16* xh = (_Float16*)d_ws;                          // 33,554,432 B
    _Float16* wh = (_Float16*)((char*)d_ws + 33554432ull);   // 90,177,536 B

    cvt_x_kernel<<<2048, 256, 0, stream>>>(x, xh);
    dequant_w_kernel<<<2048, 256, 0, stream>>>(wp, scales, wh);

    // 16 Mtiles x 43 Ntiles = 688 blocks (= 8 XCDs x 86 exactly)
    gemm_kernel<<<688, 512, 0, stream>>>(xh, wh, bias, out);
}